// Round 17
// baseline (33.603 us; speedup 1.0000x reference)
//
#include <hip/hip_runtime.h>
#include <hip/hip_bf16.h>
#include <math.h>

#define GRID_D 362
#define GRID_H 181              // GRID_D/2 (float2)
#define NKEYS  10000
#define NKPAD  10240            // KSPLIT * 4 waves * 64 * MITER
#define NT32   320              // NKPAD/32
#define EPSV   1e-8f
#define MROWS  16               // rows per main block (one 16x16 MFMA tile)
#define FROWS  16               // rows per final block
#define NTHR   256
#define RPB    16               // rows per prep block
#define KSPLIT 8
#define KPS    1280             // NKPAD/KSPLIT
#define MITER  5                // KPS / (4 waves * 64)
#define PACKB  128              // keys per pack block
#define LOG2E  1.4426950408889634f
#define LN2    0.6931471805599453f

typedef unsigned short u16;
typedef unsigned int   u32;
typedef __attribute__((ext_vector_type(8))) short bf16x8;
typedef __attribute__((ext_vector_type(4))) float f32x4;

__device__ __forceinline__ u16 f2bf(float x) {
    __hip_bfloat16 b = __float2bfloat16(x);
    return *reinterpret_cast<u16*>(&b);
}

// ---------------- prep: row-prep(+out_x copy) | bucket-scan | fused K/V pack ----------------
__global__ __launch_bounds__(256) void prep_pack_kernel(
    const float* __restrict__ batch_x,
    const int*   __restrict__ batch_a,
    const float* __restrict__ keys,      // [3,10000,6]
    const float* __restrict__ values,    // [3,10000,7]
    int*   __restrict__ cnt,             // [4]
    int*   __restrict__ rowlist,         // [3*B]
    float* __restrict__ qout,            // [B*6] scaled by LOG2E
    int*   __restrict__ cellout,         // [B*6]
    uint4* __restrict__ kfc,             // [3*NKPAD] K frags (16B/key)
    uint4* __restrict__ vfrag,           // [3*NT32*32] V frags, compact cols 0..7
    float* __restrict__ out_x,           // [B*362] baseline copy
    int B, int prep_blocks)
{
    const int bid  = blockIdx.x;
    const int tid  = threadIdx.x;
    const int lane = tid & 63;
    const int w    = tid >> 6;

    if (bid > prep_blocks) {
        // ---- pack block: 128 contiguous keys, LDS-staged coalesced ----
        __shared__ float s_kraw[PACKB * 6];
        __shared__ float s_vraw[PACKB * 7];
        const int pb     = bid - prep_blocks - 1;     // 0..239
        const int a      = pb / 80;
        const int kchunk = (pb - a * 80) * PACKB;     // 0..10112
        const int nk     = min(PACKB, NKEYS - kchunk);// may be <=0 (all-pad chunk)

        if (nk > 0) {
            const float* kg = keys   + ((size_t)a * NKEYS + kchunk) * 6;
            const float* vg = values + ((size_t)a * NKEYS + kchunk) * 7;
            for (int i = tid; i < nk * 6; i += 256) s_kraw[i] = kg[i];
            for (int i = tid; i < nk * 7; i += 256) s_vraw[i] = vg[i];
        }
        __syncthreads();

        if (tid < PACKB) {
            // kfc: threads 0..127 -> one key each (coalesced uint4 write)
            uint4 o = make_uint4(0u, 0u, 0u, 0u);
            if (tid < nk) {
                const float* k = s_kraw + tid * 6;
                const float k0=k[0],k1=k[1],k2=k[2],k3=k[3],k4=k[4],k5=k[5];
                const float nn = k0*k0+k1*k1+k2*k2+k3*k3+k4*k4+k5*k5;
                const float invn = 1.f/(sqrtf(nn)+EPSV);
                o.x = (u32)f2bf(k0*invn) | ((u32)f2bf(k1*invn) << 16);
                o.y = (u32)f2bf(k2*invn) | ((u32)f2bf(k3*invn) << 16);
                o.z = (u32)f2bf(k4*invn) | ((u32)f2bf(k5*invn) << 16);
            }
            kfc[(size_t)a * NKPAD + kchunk + tid] = o;
        } else {
            // vfrag compact: threads 128..255 -> 128 entries = 4 t32 tiles x 32
            const int e   = tid - 128;           // 0..127
            const int t32 = e >> 5;              // local tile 0..3
            const int ee  = e & 31;
            const int g   = ee >> 3;             // k-group 0..3
            const int col = ee & 7;              // v-col 0..7
            const int kloc0 = t32 * 32 + g * 8;  // local key of j=0
            u16 u[8];
#pragma unroll
            for (int j = 0; j < 8; ++j) {
                const int kl = kloc0 + j;
                float v = 0.f;
                if (kl < nk) {
                    if (col < 7) v = s_vraw[kl * 7 + col];
                    else         v = 1.f;        // sumexp column
                }
                u[j] = f2bf(v);
            }
            uint4 o;
            o.x = (u32)u[0] | ((u32)u[1] << 16);
            o.y = (u32)u[2] | ((u32)u[3] << 16);
            o.z = (u32)u[4] | ((u32)u[5] << 16);
            o.w = (u32)u[6] | ((u32)u[7] << 16);
            vfrag[((size_t)a * NT32 + (kchunk >> 5) + t32) * 32 + ee] = o;
        }
        return;
    }
    if (bid == prep_blocks) {
        // ---- bucket-scan block: stable partition of rows by a, no atomics ----
        __shared__ int s_wsum[3][4];
        int as[16];
        int c0 = 0, c1 = 0, c2 = 0;
#pragma unroll
        for (int i = 0; i < 16; ++i) {
            const int b = tid * 16 + i;
            const int aa = (b < B) ? batch_a[b] : -1;
            as[i] = aa;
            c0 += (aa == 0); c1 += (aa == 1); c2 += (aa == 2);
        }
        int x0 = c0, x1 = c1, x2 = c2;
#pragma unroll
        for (int off = 1; off < 64; off <<= 1) {
            const int y0 = __shfl_up(x0, off);
            const int y1 = __shfl_up(x1, off);
            const int y2 = __shfl_up(x2, off);
            if (lane >= off) { x0 += y0; x1 += y1; x2 += y2; }
        }
        if (lane == 63) { s_wsum[0][w] = x0; s_wsum[1][w] = x1; s_wsum[2][w] = x2; }
        __syncthreads();
        int b0 = 0, b1 = 0, b2 = 0;
        for (int ww = 0; ww < w; ++ww) {
            b0 += s_wsum[0][ww]; b1 += s_wsum[1][ww]; b2 += s_wsum[2][ww];
        }
        int o0 = b0 + x0 - c0;
        int o1 = b1 + x1 - c1;
        int o2 = b2 + x2 - c2;
#pragma unroll
        for (int i = 0; i < 16; ++i) {
            const int b = tid * 16 + i;
            if (b >= B) break;
            const int aa = as[i];
            if      (aa == 0) rowlist[0 * B + (o0++)] = b;
            else if (aa == 1) rowlist[1 * B + (o1++)] = b;
            else if (aa == 2) rowlist[2 * B + (o2++)] = b;
        }
        if (tid == 0) {
#pragma unroll
            for (int aa = 0; aa < 3; ++aa)
                cnt[aa] = s_wsum[aa][0] + s_wsum[aa][1] + s_wsum[aa][2] + s_wsum[aa][3];
        }
        return;
    }

    // ---- row-prep: 16 rows/block (4 waves x 4 rows), float2-vectorized ----
    const int b0r = bid * RPB;
    for (int rr = 0; rr < RPB / 4; ++rr) {
        const int b = b0r + rr * 4 + w;
        if (b >= B) continue;
        const float*  x  = batch_x + (size_t)b * GRID_D;
        float*        o  = out_x   + (size_t)b * GRID_D;
        const float2* x2 = (const float2*)x;          // row stride 1448B: 8B-aligned
        float2*       o2 = (float2*)o;

        float bestv = -INFINITY;
        int   besti = 1 << 30;
        {
            const float2 v0 = x2[lane];
            o2[lane] = v0;
            if (v0.x > bestv) { bestv = v0.x; besti = 2 * lane; }
            if (v0.y > bestv) { bestv = v0.y; besti = 2 * lane + 1; }
            const float2 v1 = x2[64 + lane];
            o2[64 + lane] = v1;
            if (v1.x > bestv) { bestv = v1.x; besti = 2 * (64 + lane); }
            if (v1.y > bestv) { bestv = v1.y; besti = 2 * (64 + lane) + 1; }
            if (lane < GRID_H - 128) {
                const float2 v2 = x2[128 + lane];
                o2[128 + lane] = v2;
                if (v2.x > bestv) { bestv = v2.x; besti = 2 * (128 + lane); }
                if (v2.y > bestv) { bestv = v2.y; besti = 2 * (128 + lane) + 1; }
            }
        }
#pragma unroll
        for (int off = 32; off > 0; off >>= 1) {
            const float ov = __shfl_down(bestv, off);
            const int   oi = __shfl_down(besti, off);
            if (ov > bestv || (ov == bestv && oi < besti)) { bestv = ov; besti = oi; }
        }
        const int ptr = __shfl(besti, 0);

        int cc = 0;
        if      (lane == 1) cc = ptr;
        else if (lane == 2) cc = min(max(ptr - 19, 1), GRID_D - 1);
        else if (lane == 3) cc = min(max(ptr + 19, 1), GRID_D - 1);
        else if (lane == 4) cc = min(max(ptr - 1,  1), GRID_D - 1);
        else if (lane == 5) cc = min(max(ptr + 1,  1), GRID_D - 1);
        float att = 0.f;
        if (lane < 6) att = x[cc];                    // L1-hot
        float sq = att * att;
        sq += __shfl_xor(sq, 1);
        sq += __shfl_xor(sq, 2);
        sq += __shfl_xor(sq, 4);
        if (lane < 6) {
            const float inv = 1.f / (sqrtf(sq) + EPSV);
            qout[b * 6 + lane]    = att * inv * LOG2E;
            cellout[b * 6 + lane] = cc;
        }
    }
}

// ---------------- main: MFMA QK^T (A=K, B=Q) + MFMA PV, register double-buffered ----------------
__global__ __launch_bounds__(NTHR) void main_kernel(
    const uint4* __restrict__ kfc,
    const uint4* __restrict__ vfrag,
    const int*   __restrict__ cnt,
    const int*   __restrict__ rowlist,
    const float* __restrict__ qin,
    float* __restrict__ partial,         // [KSPLIT][B][9]
    int B)
{
    const int cnt0 = cnt[0], cnt1 = cnt[1], cnt2 = cnt[2];
    const int ch0 = (cnt0 + MROWS - 1) / MROWS;
    const int ch1 = (cnt1 + MROWS - 1) / MROWS;
    const int ch2 = (cnt2 + MROWS - 1) / MROWS;
    const int bx  = blockIdx.x;
    int a, base, count;
    if      (bx < ch0)             { a = 0; base = bx * MROWS;               count = cnt0; }
    else if (bx < ch0 + ch1)       { a = 1; base = (bx - ch0) * MROWS;       count = cnt1; }
    else if (bx < ch0 + ch1 + ch2) { a = 2; base = (bx - ch0 - ch1) * MROWS; count = cnt2; }
    else return;

    const int tid  = threadIdx.x;
    const int lane = tid & 63;
    const int w    = tid >> 6;
    const int z    = blockIdx.y;

    __shared__ int   s_row[MROWS];
    __shared__ float s_q[MROWS][6];
    __shared__ __align__(16) u16 s_e[4][1024];   // per-wave [16 rows][64 keys], XOR-swizzled
    __shared__ float s_cred[4][MROWS][8];
    __shared__ float s_redm[4][MROWS];

    if (tid < MROWS)
        s_row[tid] = (base + tid < count) ? rowlist[a * B + base + tid] : -1;
    if (tid < MROWS * 6) {
        const int r = tid / 6, j = tid % 6;
        const int row = (base + r < count) ? rowlist[a * B + base + r] : -1;
        s_q[r][j] = (row >= 0) ? qin[row * 6 + j] : 0.f;
    }
    __syncthreads();

    // Q as B-fragment: col = lane&15 = q-row, k = (lane>>4)*8+j (k>=8 zero)
    bf16x8 aq = {0,0,0,0,0,0,0,0};
    if (lane < 16) {
#pragma unroll
        for (int j = 0; j < 6; ++j) aq[j] = (short)f2bf(s_q[lane][j]);
    }

    const int l15 = lane & 15;
    const int h4  = lane >> 4;
    const int swz = (l15 & 7) << 3;

    const int waddr0 = l15 * 64 + ((h4 * 4) ^ swz);
    const int ridx0  = l15 * 64 + ((h4 * 8) ^ swz);

    f32x4 c = {0.f, 0.f, 0.f, 0.f};
    float m = -INFINITY;

    const int kb0 = z * KPS + w * 64;                 // wave's first key
    const uint4* kfp = kfc + (size_t)a * NKPAD + kb0 + l15;
    const uint4* vfp = vfrag + ((size_t)a * NT32 + (kb0 >> 5)) * 32 + (h4 * 8 + (l15 & 7));
    const f32x4 zc = {0.f, 0.f, 0.f, 0.f};
    const bool kload = (lane < 16);
    const bool vload = (l15 < 8);

    // -------- prologue: load it=0 tiles into current regs --------
    uint4 ck0 = make_uint4(0u,0u,0u,0u), ck1 = ck0, ck2 = ck0, ck3 = ck0;
    uint4 cv0 = ck0, cv1 = ck0;
    if (kload) { ck0 = kfp[0]; ck1 = kfp[16]; ck2 = kfp[32]; ck3 = kfp[48]; }
    if (vload) { cv0 = vfp[0]; cv1 = vfp[32]; }
    kfp += 256; vfp += 256;

#pragma unroll 1
    for (int it = 0; it < MITER; ++it) {
        // -------- prefetch it+1 (issues before current compute; latency hidden) --------
        uint4 nk0 = make_uint4(0u,0u,0u,0u), nk1 = nk0, nk2 = nk0, nk3 = nk0;
        uint4 nv0 = nk0, nv1 = nk0;
        const bool more = (it + 1 < MITER);
        if (more) {
            if (kload) { nk0 = kfp[0]; nk1 = kfp[16]; nk2 = kfp[32]; nk3 = kfp[48]; }
            if (vload) { nv0 = vfp[0]; nv1 = vfp[32]; }
        }

        const bf16x8 b0 = *reinterpret_cast<const bf16x8*>(&cv0);
        const bf16x8 b1 = *reinterpret_cast<const bf16x8*>(&cv1);
        const int kbase = kb0 + it * 256;

#pragma unroll
        for (int tp = 0; tp < 2; ++tp) {              // tile pairs {0,1},{2,3}
            const uint4 u0 = (tp == 0) ? ck0 : ck2;
            const uint4 u1 = (tp == 0) ? ck1 : ck3;
            const bf16x8 kf0 = *reinterpret_cast<const bf16x8*>(&u0);
            const bf16x8 kf1 = *reinterpret_cast<const bf16x8*>(&u1);
            // A = K (rows = keys), B = Q (cols = q-rows)
            const f32x4 cs0 = __builtin_amdgcn_mfma_f32_16x16x32_bf16(kf0, aq, zc, 0, 0, 0);
            const f32x4 cs1 = __builtin_amdgcn_mfma_f32_16x16x32_bf16(kf1, aq, zc, 0, 0, 0);
            const bool kv0 = (kbase + tp * 32)      < NKEYS;   // wave-uniform, 16-aligned
            const bool kv1 = (kbase + tp * 32 + 16) < NKEYS;
            if (kv0) m = fmaxf(m, fmaxf(fmaxf(cs0[0], cs0[1]), fmaxf(cs0[2], cs0[3])));
            if (kv1) m = fmaxf(m, fmaxf(fmaxf(cs1[0], cs1[1]), fmaxf(cs1[2], cs1[3])));
            // e -> bf16 (truncation; bias cancels in softmax), one b64 write per tile
            {
                const u32 e0 = __float_as_uint(__builtin_amdgcn_exp2f(cs0[0]));
                const u32 e1 = __float_as_uint(__builtin_amdgcn_exp2f(cs0[1]));
                const u32 e2 = __float_as_uint(__builtin_amdgcn_exp2f(cs0[2]));
                const u32 e3 = __float_as_uint(__builtin_amdgcn_exp2f(cs0[3]));
                const u32 lo = (e0 >> 16) | (e1 & 0xFFFF0000u);
                const u32 hi = (e2 >> 16) | (e3 & 0xFFFF0000u);
                *(uint2*)&s_e[w][waddr0 ^ ((tp * 2) << 4)] = make_uint2(lo, hi);
            }
            {
                const u32 e0 = __float_as_uint(__builtin_amdgcn_exp2f(cs1[0]));
                const u32 e1 = __float_as_uint(__builtin_amdgcn_exp2f(cs1[1]));
                const u32 e2 = __float_as_uint(__builtin_amdgcn_exp2f(cs1[2]));
                const u32 e3 = __float_as_uint(__builtin_amdgcn_exp2f(cs1[3]));
                const u32 lo = (e0 >> 16) | (e1 & 0xFFFF0000u);
                const u32 hi = (e2 >> 16) | (e3 & 0xFFFF0000u);
                *(uint2*)&s_e[w][waddr0 ^ ((tp * 2 + 1) << 4)] = make_uint2(lo, hi);
            }
        }

        const bf16x8 pa0 = *(const bf16x8*)&s_e[w][ridx0];
        const bf16x8 pa1 = *(const bf16x8*)&s_e[w][ridx0 ^ 32];
        c = __builtin_amdgcn_mfma_f32_16x16x32_bf16(pa0, b0, c, 0, 0, 0);
        c = __builtin_amdgcn_mfma_f32_16x16x32_bf16(pa1, b1, c, 0, 0, 0);

        // -------- rotate buffers --------
        if (more) {
            ck0 = nk0; ck1 = nk1; ck2 = nk2; ck3 = nk3;
            cv0 = nv0; cv1 = nv1;
        }
        kfp += 256;
        vfp += 256;
    }

    // ---- per-row max: thread has row l15's max over its keys; fold h4 ----
    m = fmaxf(m, __shfl_xor(m, 16));
    m = fmaxf(m, __shfl_xor(m, 32));
    if (lane < 16) s_redm[w][l15] = m;

    // ---- C tile (16 q-rows x 8 v-cols) -> LDS ----
    if (l15 < 8) {
#pragma unroll
        for (int g = 0; g < 4; ++g) s_cred[w][h4 * 4 + g][l15] = c[g];
    }
    __syncthreads();

    // ---- cross-wave combine, write partials ----
    if (tid < 128) {
        const int r = tid >> 3, ci = tid & 7;
        const int row = s_row[r];
        if (row >= 0) {
            const float t = s_cred[0][r][ci] + s_cred[1][r][ci] +
                            s_cred[2][r][ci] + s_cred[3][r][ci];
            const int p = (ci == 7) ? 0 : (ci + 1);
            partial[((size_t)z * B + row) * 9 + p] = t;
        }
    } else if (tid < 128 + MROWS) {
        const int r = tid - 128;
        const int row = s_row[r];
        if (row >= 0) {
            const float mm = fmaxf(fmaxf(s_redm[0][r], s_redm[1][r]),
                                   fmaxf(s_redm[2][r], s_redm[3][r]));
            partial[((size_t)z * B + row) * 9 + 8] = mm * LN2;
        }
    }
}

// ---------------- finalize: combine splits, write 6 cells + unc + done per row ----------------
__global__ __launch_bounds__(256) void final_kernel(
    const float* __restrict__ batch_x,
    const float* __restrict__ partial,   // [KSPLIT][B][9]
    const int*   __restrict__ cellin,
    float* __restrict__ out_x,           // baseline already copied by prep
    float* __restrict__ out_unc,
    float* __restrict__ out_done,
    int B)
{
    const int b0  = blockIdx.x * FROWS;
    const int tid = threadIdx.x;

    __shared__ float s_tot[FROWS][9];
    __shared__ int   s_cell[FROWS][6];

    if (tid < FROWS * 9) {                       // 144 threads
        const int r = tid / 9, p = tid % 9;
        const int row = b0 + r;
        if (row < B) {
            float v = partial[(size_t)row * 9 + p];
#pragma unroll
            for (int z = 1; z < KSPLIT; ++z) {
                const float u = partial[((size_t)z * B + row) * 9 + p];
                v = (p == 8) ? fmaxf(v, u) : (v + u);
            }
            s_tot[r][p] = v;
        }
    } else if (tid >= 160 && tid < 160 + FROWS * 6) {   // 96 threads
        const int t = tid - 160, r = t / 6, j = t % 6;
        if (b0 + r < B) s_cell[r][j] = cellin[(b0 + r) * 6 + j];
    }
    __syncthreads();

    if (tid < FROWS) {
        const int r = tid, row = b0 + r;
        if (row < B) {
            const float inv = 1.f / s_tot[r][0];
            out_done[row] = s_tot[r][7] * inv;
            out_unc[row]  = -s_tot[r][8];
            float* orow = out_x + (size_t)row * GRID_D;
            const float* xrow = batch_x + (size_t)row * GRID_D;
#pragma unroll
            for (int j = 0; j < 6; ++j) {         // ascending j, same thread: last wins
                const int cc = s_cell[r][j];
                orow[cc] = xrow[cc] + s_tot[r][1 + j] * inv;
            }
        }
    }
}

extern "C" void kernel_launch(void* const* d_in, const int* in_sizes, int n_in,
                              void* d_out, int out_size, void* d_ws, size_t ws_size,
                              hipStream_t stream) {
    const float* batch_x = (const float*)d_in[0];
    const int*   batch_a = (const int*)d_in[1];
    const float* keys    = (const float*)d_in[2];
    const float* values  = (const float*)d_in[3];
    const int B = in_sizes[1];                 // 4096

    float* out      = (float*)d_out;
    float* out_x    = out;
    float* out_unc  = out + (size_t)B * GRID_D;
    float* out_done = out_unc + B;

    // workspace layout (no memset needed: cnt/rowlist fully written by bucket block)
    int*   cnt     = (int*)d_ws;                         // 4
    int*   rowlist = cnt + 4;                            // 3*B
    float* qbuf    = (float*)(rowlist + 3 * B);          // B*6
    int*   cellbuf = (int*)(qbuf + (size_t)B * 6);       // B*6
    float* partial = (float*)(cellbuf + (size_t)B * 6);  // KSPLIT*B*9
    uint4* kfc     = (uint4*)(partial + (size_t)KSPLIT * B * 9); // 3*NKPAD
    uint4* vfrag   = kfc + (size_t)3 * NKPAD;            // 3*NT32*32 (compact)

    const int prep_blocks = (B + RPB - 1) / RPB;         // 256
    const int grid_prep   = prep_blocks + 1 + 240;       // rows | bucket | packs
    prep_pack_kernel<<<grid_prep, 256, 0, stream>>>(
        batch_x, batch_a, keys, values, cnt, rowlist, qbuf, cellbuf,
        kfc, vfrag, out_x, B, prep_blocks);

    const int chunks_m = (B + MROWS - 1) / MROWS + 3;    // flattened upper bound (259)
    main_kernel<<<dim3(chunks_m, KSPLIT), NTHR, 0, stream>>>(
        kfc, vfrag, cnt, rowlist, qbuf, partial, B);

    const int chunks_f = (B + FROWS - 1) / FROWS;        // 256
    final_kernel<<<dim3(chunks_f), 256, 0, stream>>>(
        batch_x, partial, cellbuf, out_x, out_unc, out_done, B);
}

// Round 18
// 31.536 us; speedup vs baseline: 1.0656x; 1.0656x over previous
//
#include <hip/hip_runtime.h>
#include <hip/hip_bf16.h>
#include <math.h>

#define GRID_D 362
#define GRID_H 181              // GRID_D/2 (float2)
#define NKEYS  10000
#define NKPAD  10240            // KSPLIT * 4 waves * 64 * MITER
#define NT32   320              // NKPAD/32
#define EPSV   1e-8f
#define MROWS  16               // rows per main block (one 16x16 MFMA tile)
#define FROWS  16               // rows per final block
#define NTHR   256
#define RPB    16               // rows per prep block
#define KSPLIT 8
#define KPS    1280             // NKPAD/KSPLIT
#define MITER  5                // KPS / (4 waves * 64)
#define PACKB  128              // keys per pack block
#define LOG2E  1.4426950408889634f
#define LN2    0.6931471805599453f

typedef unsigned short u16;
typedef unsigned int   u32;
typedef __attribute__((ext_vector_type(8))) short bf16x8;
typedef __attribute__((ext_vector_type(4))) float f32x4;

__device__ __forceinline__ u16 f2bf(float x) {
    __hip_bfloat16 b = __float2bfloat16(x);
    return *reinterpret_cast<u16*>(&b);
}

// ---------------- prep: row-prep(+out_x copy) | bucket-scan | fused K/V pack ----------------
__global__ __launch_bounds__(256) void prep_pack_kernel(
    const float* __restrict__ batch_x,
    const int*   __restrict__ batch_a,
    const float* __restrict__ keys,      // [3,10000,6]
    const float* __restrict__ values,    // [3,10000,7]
    int*   __restrict__ cnt,             // [4]
    int*   __restrict__ rowlist,         // [3*B]
    float* __restrict__ qout,            // [B*6] scaled by LOG2E
    int*   __restrict__ cellout,         // [B*6]
    uint4* __restrict__ kfc,             // [3*NKPAD] K frags (16B/key)
    uint4* __restrict__ vfrag,           // [3*NT32*32] V frags, compact cols 0..7
    float* __restrict__ out_x,           // [B*362] baseline copy
    int B, int prep_blocks)
{
    const int bid  = blockIdx.x;
    const int tid  = threadIdx.x;
    const int lane = tid & 63;
    const int w    = tid >> 6;

    if (bid > prep_blocks) {
        // ---- pack block: 128 contiguous keys, LDS-staged coalesced ----
        __shared__ float s_kraw[PACKB * 6];
        __shared__ float s_vraw[PACKB * 7];
        const int pb     = bid - prep_blocks - 1;     // 0..239
        const int a      = pb / 80;
        const int kchunk = (pb - a * 80) * PACKB;     // 0..10112
        const int nk     = min(PACKB, NKEYS - kchunk);// may be <=0 (all-pad chunk)

        if (nk > 0) {
            const float* kg = keys   + ((size_t)a * NKEYS + kchunk) * 6;
            const float* vg = values + ((size_t)a * NKEYS + kchunk) * 7;
            for (int i = tid; i < nk * 6; i += 256) s_kraw[i] = kg[i];
            for (int i = tid; i < nk * 7; i += 256) s_vraw[i] = vg[i];
        }
        __syncthreads();

        if (tid < PACKB) {
            // kfc: threads 0..127 -> one key each (coalesced uint4 write)
            uint4 o = make_uint4(0u, 0u, 0u, 0u);
            if (tid < nk) {
                const float* k = s_kraw + tid * 6;
                const float k0=k[0],k1=k[1],k2=k[2],k3=k[3],k4=k[4],k5=k[5];
                const float nn = k0*k0+k1*k1+k2*k2+k3*k3+k4*k4+k5*k5;
                const float invn = 1.f/(sqrtf(nn)+EPSV);
                o.x = (u32)f2bf(k0*invn) | ((u32)f2bf(k1*invn) << 16);
                o.y = (u32)f2bf(k2*invn) | ((u32)f2bf(k3*invn) << 16);
                o.z = (u32)f2bf(k4*invn) | ((u32)f2bf(k5*invn) << 16);
            }
            kfc[(size_t)a * NKPAD + kchunk + tid] = o;
        } else {
            // vfrag compact: threads 128..255 -> 128 entries = 4 t32 tiles x 32
            // entry (t32, g, col): col = v-col 0..7 (7=ones), k = g*8+j
            const int e   = tid - 128;           // 0..127
            const int t32 = e >> 5;              // local tile 0..3
            const int ee  = e & 31;
            const int g   = ee >> 3;             // k-group 0..3
            const int col = ee & 7;              // v-col 0..7
            const int kloc0 = t32 * 32 + g * 8;  // local key of j=0
            u16 u[8];
#pragma unroll
            for (int j = 0; j < 8; ++j) {
                const int kl = kloc0 + j;
                float v = 0.f;
                if (kl < nk) {
                    if (col < 7) v = s_vraw[kl * 7 + col];
                    else         v = 1.f;        // sumexp column
                }
                u[j] = f2bf(v);
            }
            uint4 o;
            o.x = (u32)u[0] | ((u32)u[1] << 16);
            o.y = (u32)u[2] | ((u32)u[3] << 16);
            o.z = (u32)u[4] | ((u32)u[5] << 16);
            o.w = (u32)u[6] | ((u32)u[7] << 16);
            vfrag[((size_t)a * NT32 + (kchunk >> 5) + t32) * 32 + ee] = o;
        }
        return;
    }
    if (bid == prep_blocks) {
        // ---- bucket-scan block: stable partition of rows by a, no atomics ----
        __shared__ int s_wsum[3][4];
        int as[16];
        int c0 = 0, c1 = 0, c2 = 0;
#pragma unroll
        for (int i = 0; i < 16; ++i) {
            const int b = tid * 16 + i;
            const int aa = (b < B) ? batch_a[b] : -1;
            as[i] = aa;
            c0 += (aa == 0); c1 += (aa == 1); c2 += (aa == 2);
        }
        int x0 = c0, x1 = c1, x2 = c2;
#pragma unroll
        for (int off = 1; off < 64; off <<= 1) {
            const int y0 = __shfl_up(x0, off);
            const int y1 = __shfl_up(x1, off);
            const int y2 = __shfl_up(x2, off);
            if (lane >= off) { x0 += y0; x1 += y1; x2 += y2; }
        }
        if (lane == 63) { s_wsum[0][w] = x0; s_wsum[1][w] = x1; s_wsum[2][w] = x2; }
        __syncthreads();
        int b0 = 0, b1 = 0, b2 = 0;
        for (int ww = 0; ww < w; ++ww) {
            b0 += s_wsum[0][ww]; b1 += s_wsum[1][ww]; b2 += s_wsum[2][ww];
        }
        int o0 = b0 + x0 - c0;
        int o1 = b1 + x1 - c1;
        int o2 = b2 + x2 - c2;
#pragma unroll
        for (int i = 0; i < 16; ++i) {
            const int b = tid * 16 + i;
            if (b >= B) break;
            const int aa = as[i];
            if      (aa == 0) rowlist[0 * B + (o0++)] = b;
            else if (aa == 1) rowlist[1 * B + (o1++)] = b;
            else if (aa == 2) rowlist[2 * B + (o2++)] = b;
        }
        if (tid == 0) {
#pragma unroll
            for (int aa = 0; aa < 3; ++aa)
                cnt[aa] = s_wsum[aa][0] + s_wsum[aa][1] + s_wsum[aa][2] + s_wsum[aa][3];
        }
        return;
    }

    // ---- row-prep: 16 rows/block (4 waves x 4 rows), float2-vectorized ----
    const int b0r = bid * RPB;
    for (int rr = 0; rr < RPB / 4; ++rr) {
        const int b = b0r + rr * 4 + w;
        if (b >= B) continue;
        const float*  x  = batch_x + (size_t)b * GRID_D;
        float*        o  = out_x   + (size_t)b * GRID_D;
        const float2* x2 = (const float2*)x;          // row stride 1448B: 8B-aligned
        float2*       o2 = (float2*)o;

        float bestv = -INFINITY;
        int   besti = 1 << 30;
        {   // i2 = lane, lane+64 always < 181; lane+128 < 181 iff lane < 53
            const float2 v0 = x2[lane];
            o2[lane] = v0;
            if (v0.x > bestv) { bestv = v0.x; besti = 2 * lane; }
            if (v0.y > bestv) { bestv = v0.y; besti = 2 * lane + 1; }
            const float2 v1 = x2[64 + lane];
            o2[64 + lane] = v1;
            if (v1.x > bestv) { bestv = v1.x; besti = 2 * (64 + lane); }
            if (v1.y > bestv) { bestv = v1.y; besti = 2 * (64 + lane) + 1; }
            if (lane < GRID_H - 128) {
                const float2 v2 = x2[128 + lane];
                o2[128 + lane] = v2;
                if (v2.x > bestv) { bestv = v2.x; besti = 2 * (128 + lane); }
                if (v2.y > bestv) { bestv = v2.y; besti = 2 * (128 + lane) + 1; }
            }
        }
#pragma unroll
        for (int off = 32; off > 0; off >>= 1) {
            const float ov = __shfl_down(bestv, off);
            const int   oi = __shfl_down(besti, off);
            if (ov > bestv || (ov == bestv && oi < besti)) { bestv = ov; besti = oi; }
        }
        const int ptr = __shfl(besti, 0);

        // lanes 0..5 each own one cell; ss via shfl_xor over closed 8-lane group
        int cc = 0;
        if      (lane == 1) cc = ptr;
        else if (lane == 2) cc = min(max(ptr - 19, 1), GRID_D - 1);
        else if (lane == 3) cc = min(max(ptr + 19, 1), GRID_D - 1);
        else if (lane == 4) cc = min(max(ptr - 1,  1), GRID_D - 1);
        else if (lane == 5) cc = min(max(ptr + 1,  1), GRID_D - 1);
        float att = 0.f;
        if (lane < 6) att = x[cc];                    // L1-hot
        float sq = att * att;
        sq += __shfl_xor(sq, 1);
        sq += __shfl_xor(sq, 2);
        sq += __shfl_xor(sq, 4);                      // lanes 0..7 hold full sum (6,7 were 0)
        if (lane < 6) {
            const float inv = 1.f / (sqrtf(sq) + EPSV);
            qout[b * 6 + lane]    = att * inv * LOG2E;
            cellout[b * 6 + lane] = cc;
        }
    }
}

// ---------------- main: MFMA QK^T (A=K, B=Q) + MFMA PV, flattened chunk grid ----------------
// vfrag is compact (cols 0..7 only): lanes l15>=8 hold zero B operands without
// streaming zeros from memory (halves the V stream).
__global__ __launch_bounds__(NTHR) void main_kernel(
    const uint4* __restrict__ kfc,
    const uint4* __restrict__ vfrag,
    const int*   __restrict__ cnt,
    const int*   __restrict__ rowlist,
    const float* __restrict__ qin,
    float* __restrict__ partial,         // [KSPLIT][B][9]
    int B)
{
    // flattened (a, base) from blockIdx.x via 3-bucket chunk prefix (SGPR math)
    const int cnt0 = cnt[0], cnt1 = cnt[1], cnt2 = cnt[2];
    const int ch0 = (cnt0 + MROWS - 1) / MROWS;
    const int ch1 = (cnt1 + MROWS - 1) / MROWS;
    const int ch2 = (cnt2 + MROWS - 1) / MROWS;
    const int bx  = blockIdx.x;
    int a, base, count;
    if      (bx < ch0)             { a = 0; base = bx * MROWS;               count = cnt0; }
    else if (bx < ch0 + ch1)       { a = 1; base = (bx - ch0) * MROWS;       count = cnt1; }
    else if (bx < ch0 + ch1 + ch2) { a = 2; base = (bx - ch0 - ch1) * MROWS; count = cnt2; }
    else return;

    const int tid  = threadIdx.x;
    const int lane = tid & 63;
    const int w    = tid >> 6;
    const int z    = blockIdx.y;

    __shared__ int   s_row[MROWS];
    __shared__ float s_q[MROWS][6];
    __shared__ __align__(16) u16 s_e[4][1024];   // per-wave [16 rows][64 keys], XOR-swizzled
    __shared__ float s_cred[4][MROWS][8];
    __shared__ float s_redm[4][MROWS];

    if (tid < MROWS)
        s_row[tid] = (base + tid < count) ? rowlist[a * B + base + tid] : -1;
    if (tid < MROWS * 6) {
        const int r = tid / 6, j = tid % 6;
        const int row = (base + r < count) ? rowlist[a * B + base + r] : -1;
        s_q[r][j] = (row >= 0) ? qin[row * 6 + j] : 0.f;
    }
    __syncthreads();

    // Q as B-fragment: col = lane&15 = q-row, k = (lane>>4)*8+j (k>=8 zero)
    bf16x8 aq = {0,0,0,0,0,0,0,0};
    if (lane < 16) {
#pragma unroll
        for (int j = 0; j < 6; ++j) aq[j] = (short)f2bf(s_q[lane][j]);
    }

    const int l15 = lane & 15;
    const int h4  = lane >> 4;
    const int swz = (l15 & 7) << 3;

    // compressed addresses: waddr[t] = waddr0 ^ (t<<4); ridx1 = ridx0 ^ 32
    const int waddr0 = l15 * 64 + ((h4 * 4) ^ swz);
    const int ridx0  = l15 * 64 + ((h4 * 8) ^ swz);

    f32x4 c = {0.f, 0.f, 0.f, 0.f};
    float m = -INFINITY;

    const int kb0 = z * KPS + w * 64;                 // wave's first key
    const uint4* kfp = kfc + (size_t)a * NKPAD + kb0 + l15;
    // compact vfrag: per t32 tile, 32 entries (g*8+col); lanes l15>=8 don't load
    const uint4* vfp = vfrag + ((size_t)a * NT32 + (kb0 >> 5)) * 32 + (h4 * 8 + (l15 & 7));
    const f32x4 zc = {0.f, 0.f, 0.f, 0.f};

#pragma unroll 1
    for (int it = 0; it < MITER; ++it) {
        uint4 vv0 = make_uint4(0u,0u,0u,0u), vv1 = make_uint4(0u,0u,0u,0u);
        if (l15 < 8) { vv0 = vfp[0]; vv1 = vfp[32]; }
        const bf16x8 b0 = *reinterpret_cast<const bf16x8*>(&vv0);
        const bf16x8 b1 = *reinterpret_cast<const bf16x8*>(&vv1);
        const int kbase = kb0 + it * 256;

#pragma unroll
        for (int tp = 0; tp < 2; ++tp) {              // tile pairs {0,1},{2,3}
            uint4 u0 = make_uint4(0u,0u,0u,0u), u1 = make_uint4(0u,0u,0u,0u);
            if (lane < 16) { u0 = kfp[tp * 32]; u1 = kfp[tp * 32 + 16]; }
            const bf16x8 kf0 = *reinterpret_cast<bf16x8*>(&u0);
            const bf16x8 kf1 = *reinterpret_cast<bf16x8*>(&u1);
            // A = K (rows = keys), B = Q (cols = q-rows)
            const f32x4 cs0 = __builtin_amdgcn_mfma_f32_16x16x32_bf16(kf0, aq, zc, 0, 0, 0);
            const f32x4 cs1 = __builtin_amdgcn_mfma_f32_16x16x32_bf16(kf1, aq, zc, 0, 0, 0);
            const bool kv0 = (kbase + tp * 32)      < NKEYS;   // wave-uniform, 16-aligned
            const bool kv1 = (kbase + tp * 32 + 16) < NKEYS;
            if (kv0) m = fmaxf(m, fmaxf(fmaxf(cs0[0], cs0[1]), fmaxf(cs0[2], cs0[3])));
            if (kv1) m = fmaxf(m, fmaxf(fmaxf(cs1[0], cs1[1]), fmaxf(cs1[2], cs1[3])));
            // e -> bf16 (truncation; bias cancels in softmax), one b64 write per tile
            {
                const u32 e0 = __float_as_uint(__builtin_amdgcn_exp2f(cs0[0]));
                const u32 e1 = __float_as_uint(__builtin_amdgcn_exp2f(cs0[1]));
                const u32 e2 = __float_as_uint(__builtin_amdgcn_exp2f(cs0[2]));
                const u32 e3 = __float_as_uint(__builtin_amdgcn_exp2f(cs0[3]));
                const u32 lo = (e0 >> 16) | (e1 & 0xFFFF0000u);
                const u32 hi = (e2 >> 16) | (e3 & 0xFFFF0000u);
                *(uint2*)&s_e[w][waddr0 ^ ((tp * 2) << 4)] = make_uint2(lo, hi);
            }
            {
                const u32 e0 = __float_as_uint(__builtin_amdgcn_exp2f(cs1[0]));
                const u32 e1 = __float_as_uint(__builtin_amdgcn_exp2f(cs1[1]));
                const u32 e2 = __float_as_uint(__builtin_amdgcn_exp2f(cs1[2]));
                const u32 e3 = __float_as_uint(__builtin_amdgcn_exp2f(cs1[3]));
                const u32 lo = (e0 >> 16) | (e1 & 0xFFFF0000u);
                const u32 hi = (e2 >> 16) | (e3 & 0xFFFF0000u);
                *(uint2*)&s_e[w][waddr0 ^ ((tp * 2 + 1) << 4)] = make_uint2(lo, hi);
            }
        }

        const bf16x8 pa0 = *(const bf16x8*)&s_e[w][ridx0];
        const bf16x8 pa1 = *(const bf16x8*)&s_e[w][ridx0 ^ 32];
        c = __builtin_amdgcn_mfma_f32_16x16x32_bf16(pa0, b0, c, 0, 0, 0);
        c = __builtin_amdgcn_mfma_f32_16x16x32_bf16(pa1, b1, c, 0, 0, 0);

        kfp += 256;
        vfp += 256;     // 8 t32 tiles * 32 compact entries
    }

    // ---- per-row max: thread has row l15's max over its keys; fold h4 ----
    m = fmaxf(m, __shfl_xor(m, 16));
    m = fmaxf(m, __shfl_xor(m, 32));
    if (lane < 16) s_redm[w][l15] = m;

    // ---- C tile (16 q-rows x 8 v-cols) -> LDS ----
    if (l15 < 8) {
#pragma unroll
        for (int g = 0; g < 4; ++g) s_cred[w][h4 * 4 + g][l15] = c[g];
    }
    __syncthreads();

    // ---- cross-wave combine, write partials ----
    if (tid < 128) {
        const int r = tid >> 3, ci = tid & 7;
        const int row = s_row[r];
        if (row >= 0) {
            const float t = s_cred[0][r][ci] + s_cred[1][r][ci] +
                            s_cred[2][r][ci] + s_cred[3][r][ci];
            const int p = (ci == 7) ? 0 : (ci + 1);
            partial[((size_t)z * B + row) * 9 + p] = t;
        }
    } else if (tid < 128 + MROWS) {
        const int r = tid - 128;
        const int row = s_row[r];
        if (row >= 0) {
            const float mm = fmaxf(fmaxf(s_redm[0][r], s_redm[1][r]),
                                   fmaxf(s_redm[2][r], s_redm[3][r]));
            partial[((size_t)z * B + row) * 9 + 8] = mm * LN2;
        }
    }
}

// ---------------- finalize: combine splits, write 6 cells + unc + done per row ----------------
__global__ __launch_bounds__(256) void final_kernel(
    const float* __restrict__ batch_x,
    const float* __restrict__ partial,   // [KSPLIT][B][9]
    const int*   __restrict__ cellin,
    float* __restrict__ out_x,           // baseline already copied by prep
    float* __restrict__ out_unc,
    float* __restrict__ out_done,
    int B)
{
    const int b0  = blockIdx.x * FROWS;
    const int tid = threadIdx.x;

    __shared__ float s_tot[FROWS][9];
    __shared__ int   s_cell[FROWS][6];

    if (tid < FROWS * 9) {                       // 144 threads
        const int r = tid / 9, p = tid % 9;
        const int row = b0 + r;
        if (row < B) {
            float v = partial[(size_t)row * 9 + p];
#pragma unroll
            for (int z = 1; z < KSPLIT; ++z) {
                const float u = partial[((size_t)z * B + row) * 9 + p];
                v = (p == 8) ? fmaxf(v, u) : (v + u);
            }
            s_tot[r][p] = v;
        }
    } else if (tid >= 160 && tid < 160 + FROWS * 6) {   // 96 threads
        const int t = tid - 160, r = t / 6, j = t % 6;
        if (b0 + r < B) s_cell[r][j] = cellin[(b0 + r) * 6 + j];
    }
    __syncthreads();

    if (tid < FROWS) {
        const int r = tid, row = b0 + r;
        if (row < B) {
            const float inv = 1.f / s_tot[r][0];
            out_done[row] = s_tot[r][7] * inv;
            out_unc[row]  = -s_tot[r][8];
            float* orow = out_x + (size_t)row * GRID_D;
            const float* xrow = batch_x + (size_t)row * GRID_D;
#pragma unroll
            for (int j = 0; j < 6; ++j) {         // ascending j, same thread: last wins
                const int cc = s_cell[r][j];
                orow[cc] = xrow[cc] + s_tot[r][1 + j] * inv;
            }
        }
    }
}

extern "C" void kernel_launch(void* const* d_in, const int* in_sizes, int n_in,
                              void* d_out, int out_size, void* d_ws, size_t ws_size,
                              hipStream_t stream) {
    const float* batch_x = (const float*)d_in[0];
    const int*   batch_a = (const int*)d_in[1];
    const float* keys    = (const float*)d_in[2];
    const float* values  = (const float*)d_in[3];
    const int B = in_sizes[1];                 // 4096

    float* out      = (float*)d_out;
    float* out_x    = out;
    float* out_unc  = out + (size_t)B * GRID_D;
    float* out_done = out_unc + B;

    // workspace layout (no memset needed: cnt/rowlist fully written by bucket block)
    int*   cnt     = (int*)d_ws;                         // 4
    int*   rowlist = cnt + 4;                            // 3*B
    float* qbuf    = (float*)(rowlist + 3 * B);          // B*6
    int*   cellbuf = (int*)(qbuf + (size_t)B * 6);       // B*6
    float* partial = (float*)(cellbuf + (size_t)B * 6);  // KSPLIT*B*9
    uint4* kfc     = (uint4*)(partial + (size_t)KSPLIT * B * 9); // 3*NKPAD
    uint4* vfrag   = kfc + (size_t)3 * NKPAD;            // 3*NT32*32 (compact)

    const int prep_blocks = (B + RPB - 1) / RPB;         // 256
    const int grid_prep   = prep_blocks + 1 + 240;       // rows | bucket | packs
    prep_pack_kernel<<<grid_prep, 256, 0, stream>>>(
        batch_x, batch_a, keys, values, cnt, rowlist, qbuf, cellbuf,
        kfc, vfrag, out_x, B, prep_blocks);

    const int chunks_m = (B + MROWS - 1) / MROWS + 3;    // flattened upper bound (259)
    main_kernel<<<dim3(chunks_m, KSPLIT), NTHR, 0, stream>>>(
        kfc, vfrag, cnt, rowlist, qbuf, partial, B);

    const int chunks_f = (B + FROWS - 1) / FROWS;        // 256
    final_kernel<<<dim3(chunks_f), 256, 0, stream>>>(
        batch_x, partial, cellbuf, out_x, out_unc, out_done, B);
}